// Round 12
// baseline (633.041 us; speedup 1.0000x reference)
//
#include <hip/hip_runtime.h>

#define BB 8
#define CC 384
#define HWP 50176
#define SS 256
#define MM 65536
#define TOPK 9
#define GM 2048          // BB*SS emb rows
#define NKC 16           // K-split blocks for segsum
#define RFB3 1024        // refine blocks (64 m each)
#define MAPB 392         // map blocks (BB*HWP/4/256)

typedef __attribute__((ext_vector_type(8))) __bf16 bf16x8;
typedef __attribute__((ext_vector_type(16))) float fx16;
typedef __attribute__((ext_vector_type(4))) float f32x4;

__device__ __forceinline__ unsigned short f2bf_rne(float x) {
    unsigned u = __float_as_uint(x);
    unsigned r = (u + 0x7FFFu + ((u >> 16) & 1u)) >> 16;
    return (unsigned short)r;
}

__device__ __forceinline__ bf16x8 pack8(float4 v0, float4 v1) {
    bf16x8 r;
    r[0] = (__bf16)v0.x; r[1] = (__bf16)v0.y; r[2] = (__bf16)v0.z; r[3] = (__bf16)v0.w;
    r[4] = (__bf16)v1.x; r[5] = (__bf16)v1.y; r[6] = (__bf16)v1.z; r[7] = (__bf16)v1.w;
    return r;
}

__device__ __forceinline__ void gl_lds16(const void* g, void* l) {
    auto gp = (const __attribute__((address_space(1))) unsigned int*)g;
    auto lp = (__attribute__((address_space(3))) unsigned int*)l;
    __builtin_amdgcn_global_load_lds(gp, lp, 16, 0, 0);
}

// ---------------- K2: segment sums as MFMA GEMM + fused per-(kc,b) counts ----------------
template <bool ATOMIC>
__global__ __launch_bounds__(256) void k_segsum7c(const float* __restrict__ feats,
                                                  const int* __restrict__ labels,
                                                  float* __restrict__ outp,
                                                  unsigned* __restrict__ cntS) {
    __shared__ bf16x8 Fs[8][64];
    __shared__ int labL[64];
    __shared__ unsigned cnt[SS];
    int kc = blockIdx.x, cg = blockIdx.y, b = blockIdx.z;
    int t = threadIdx.x, l = t & 63, w = t >> 6;
    int c0b = cg * 64;
    int g16 = l >> 4;
    int rowl = l & 15;

    cnt[t] = 0u;   // 256 threads cover SS

    f32x4 acc[4][4];
#pragma unroll
    for (int i = 0; i < 4; i++)
#pragma unroll
        for (int j = 0; j < 4; j++) acc[i][j] = (f32x4){0.f, 0.f, 0.f, 0.f};

    const float* fb = feats + ((size_t)b * CC + c0b) * HWP;
    const int* lbase = labels + (size_t)b * HWP + kc * 3136;

    int id0 = t * 2;
    int cl = id0 >> 3, g0 = id0 & 7;
    const float* tbase = fb + (size_t)cl * HWP + kc * 3136 + g0 * 8;

    float4 ra0 = *(const float4*)(tbase + 0);
    float4 ra1 = *(const float4*)(tbase + 4);
    float4 rb0 = *(const float4*)(tbase + 8);
    float4 rb1 = *(const float4*)(tbase + 12);
    int4 rl4 = (t < 16) ? ((const int4*)lbase)[t] : (int4){0, 0, 0, 0};

    for (int tt = 0; tt < 49; tt++) {
        __syncthreads();
        if (t < 16) ((int4*)labL)[t] = rl4;
        Fs[g0][cl] = pack8(ra0, ra1);
        Fs[g0 + 1][cl] = pack8(rb0, rb1);
        if (tt + 1 < 49) {
            const float* nb_ = tbase + (size_t)(tt + 1) * 64;
            ra0 = *(const float4*)(nb_ + 0);
            ra1 = *(const float4*)(nb_ + 4);
            rb0 = *(const float4*)(nb_ + 8);
            rb1 = *(const float4*)(nb_ + 12);
            if (t < 16) rl4 = ((const int4*)(lbase + (tt + 1) * 64))[t];
        }
        __syncthreads();

        if (cg == 0 && t < 64) atomicAdd(&cnt[labL[t]], 1u);

        bf16x8 af0[4], af1[4];
#pragma unroll
        for (int rt = 0; rt < 4; rt++) {
            af0[rt] = Fs[g16][rt * 16 + rowl];
            af1[rt] = Fs[4 + g16][rt * 16 + rowl];
        }
        int4 lo0 = ((int4*)labL)[g16 * 2 + 0];
        int4 hi0 = ((int4*)labL)[g16 * 2 + 1];
        int4 lo1 = ((int4*)labL)[8 + g16 * 2 + 0];
        int4 hi1 = ((int4*)labL)[8 + g16 * 2 + 1];

#pragma unroll
        for (int st = 0; st < 4; st++) {
            int tgt = w * 64 + st * 16 + rowl;
            union { unsigned u[4]; bf16x8 v; } B;
            B.u[0] = (lo0.x == tgt ? 0x3F80u : 0u) | (lo0.y == tgt ? 0x3F800000u : 0u);
            B.u[1] = (lo0.z == tgt ? 0x3F80u : 0u) | (lo0.w == tgt ? 0x3F800000u : 0u);
            B.u[2] = (hi0.x == tgt ? 0x3F80u : 0u) | (hi0.y == tgt ? 0x3F800000u : 0u);
            B.u[3] = (hi0.z == tgt ? 0x3F80u : 0u) | (hi0.w == tgt ? 0x3F800000u : 0u);
#pragma unroll
            for (int rt = 0; rt < 4; rt++)
                acc[rt][st] = __builtin_amdgcn_mfma_f32_16x16x32_bf16(af0[rt], B.v, acc[rt][st], 0, 0, 0);
            B.u[0] = (lo1.x == tgt ? 0x3F80u : 0u) | (lo1.y == tgt ? 0x3F800000u : 0u);
            B.u[1] = (lo1.z == tgt ? 0x3F80u : 0u) | (lo1.w == tgt ? 0x3F800000u : 0u);
            B.u[2] = (hi1.x == tgt ? 0x3F80u : 0u) | (hi1.y == tgt ? 0x3F800000u : 0u);
            B.u[3] = (hi1.z == tgt ? 0x3F80u : 0u) | (hi1.w == tgt ? 0x3F800000u : 0u);
#pragma unroll
            for (int rt = 0; rt < 4; rt++)
                acc[rt][st] = __builtin_amdgcn_mfma_f32_16x16x32_bf16(af1[rt], B.v, acc[rt][st], 0, 0, 0);
        }
    }

    if (ATOMIC) {
#pragma unroll
        for (int rt = 0; rt < 4; rt++)
#pragma unroll
            for (int st = 0; st < 4; st++)
#pragma unroll
                for (int r = 0; r < 4; r++) {
                    int s = w * 64 + st * 16 + rowl;
                    int c = c0b + rt * 16 + g16 * 4 + r;
                    atomicAdd(&outp[((size_t)b * SS + s) * CC + c], acc[rt][st][r]);
                }
    } else {
        float* dst = outp + (size_t)(kc * BB + b) * SS * CC;
#pragma unroll
        for (int rt = 0; rt < 4; rt++)
#pragma unroll
            for (int st = 0; st < 4; st++)
#pragma unroll
                for (int r = 0; r < 4; r++) {
                    int s = w * 64 + st * 16 + rowl;
                    int c = c0b + rt * 16 + g16 * 4 + r;
                    dst[(size_t)s * CC + c] = acc[rt][st][r];
                }
    }
    __syncthreads();
    if (cg == 0) cntS[(kc * BB + b) * SS + t] = cnt[t];
}

// ---------------- K_prep: cvtmb (blocks 0..4095) + embfin (blocks 4096..4607) ----------------
__global__ __launch_bounds__(256) void k_prep(const float* __restrict__ mb,
                                              unsigned short* __restrict__ mbh,
                                              float* __restrict__ yn,
                                              const float* __restrict__ kcpart,
                                              const unsigned* __restrict__ cntS,
                                              float* __restrict__ emb, float* __restrict__ xn,
                                              unsigned short* __restrict__ embh) {
    int w = threadIdx.x >> 6, l = threadIdx.x & 63;
    if (blockIdx.x < MM / 16) {
        int r0 = blockIdx.x * 16 + w * 4;
#pragma unroll
        for (int i = 0; i < 4; i++) {
            int row = r0 + i;
            const float4* src = (const float4*)(mb + (size_t)row * CC);
            float4 a = src[l];
            float4 b2 = {0.f, 0.f, 0.f, 0.f};
            if (l < 32) b2 = src[64 + l];
            ushort4 ua; ua.x = f2bf_rne(a.x); ua.y = f2bf_rne(a.y); ua.z = f2bf_rne(a.z); ua.w = f2bf_rne(a.w);
            ((ushort4*)(mbh + (size_t)row * CC))[l] = ua;
            if (l < 32) {
                ushort4 ub; ub.x = f2bf_rne(b2.x); ub.y = f2bf_rne(b2.y); ub.z = f2bf_rne(b2.z); ub.w = f2bf_rne(b2.w);
                ((ushort4*)(mbh + (size_t)row * CC))[64 + l] = ub;
            }
            float s = a.x * a.x + a.y * a.y + a.z * a.z + a.w * a.w
                    + b2.x * b2.x + b2.y * b2.y + b2.z * b2.z + b2.w * b2.w;
#pragma unroll
            for (int m = 32; m; m >>= 1) s += __shfl_xor(s, m);
            if (l == 0) yn[row] = s;
        }
    } else {
        int i = (blockIdx.x - MM / 16) * 4 + w;
        int b = i >> 8, s256 = i & 255;
        float4 a0 = {0.f, 0.f, 0.f, 0.f}, a1 = {0.f, 0.f, 0.f, 0.f};
#pragma unroll 4
        for (int kc = 0; kc < NKC; kc++) {
            const float4* row = (const float4*)(kcpart + ((size_t)(kc * BB + b) * SS + s256) * CC);
            float4 v = row[l];
            a0.x += v.x; a0.y += v.y; a0.z += v.z; a0.w += v.w;
            if (l < 32) {
                float4 v1 = row[64 + l];
                a1.x += v1.x; a1.y += v1.y; a1.z += v1.z; a1.w += v1.w;
            }
        }
        float cw = (l < 49) ? (float)cntS[(l * BB + b) * SS + s256] : 0.f;
#pragma unroll
        for (int m = 32; m; m >>= 1) cw += __shfl_xor(cw, m);
        float inv = 1.f / fmaxf(cw, 1.f);

        a0.x *= inv; a0.y *= inv; a0.z *= inv; a0.w *= inv;
        a1.x *= inv; a1.y *= inv; a1.z *= inv; a1.w *= inv;
        ((float4*)(emb + (size_t)i * CC))[l] = a0;
        ushort4 u0; u0.x = f2bf_rne(a0.x); u0.y = f2bf_rne(a0.y); u0.z = f2bf_rne(a0.z); u0.w = f2bf_rne(a0.w);
        ((ushort4*)(embh + (size_t)i * CC))[l] = u0;
        if (l < 32) {
            ((float4*)(emb + (size_t)i * CC))[64 + l] = a1;
            ushort4 u1; u1.x = f2bf_rne(a1.x); u1.y = f2bf_rne(a1.y); u1.z = f2bf_rne(a1.z); u1.w = f2bf_rne(a1.w);
            ((ushort4*)(embh + (size_t)i * CC))[64 + l] = u1;
        }
        float ss = a0.x * a0.x + a0.y * a0.y + a0.z * a0.z + a0.w * a0.w
                 + a1.x * a1.x + a1.y * a1.y + a1.z * a1.z + a1.w * a1.w;
#pragma unroll
        for (int m = 32; m; m >>= 1) ss += __shfl_xor(ss, m);
        if (l == 0) xn[i] = ss;
    }
}

// ---------------- K_prep lowmem: ynorm + embfin-in-place ----------------
__global__ __launch_bounds__(256) void k_prep_lm(const float* __restrict__ mb,
                                                 float* __restrict__ yn,
                                                 float* __restrict__ emb,
                                                 const unsigned* __restrict__ cntS,
                                                 float* __restrict__ xn,
                                                 unsigned short* __restrict__ embh) {
    int w = threadIdx.x >> 6, l = threadIdx.x & 63;
    if (blockIdx.x < MM / 16) {
        int r0 = blockIdx.x * 16 + w * 4;
#pragma unroll
        for (int i = 0; i < 4; i++) {
            int row = r0 + i;
            const float4* src = (const float4*)(mb + (size_t)row * CC);
            float4 a = src[l];
            float4 b2 = {0.f, 0.f, 0.f, 0.f};
            if (l < 32) b2 = src[64 + l];
            float s = a.x * a.x + a.y * a.y + a.z * a.z + a.w * a.w
                    + b2.x * b2.x + b2.y * b2.y + b2.z * b2.z + b2.w * b2.w;
#pragma unroll
            for (int m = 32; m; m >>= 1) s += __shfl_xor(s, m);
            if (l == 0) yn[row] = s;
        }
    } else {
        int i = (blockIdx.x - MM / 16) * 4 + w;
        int b = i >> 8, s256 = i & 255;
        float4* e4 = (float4*)(emb + (size_t)i * CC);
        float4 a0 = e4[l];
        float4 a1 = {0.f, 0.f, 0.f, 0.f};
        if (l < 32) a1 = e4[64 + l];
        float cw = (l < 49) ? (float)cntS[(l * BB + b) * SS + s256] : 0.f;
#pragma unroll
        for (int m = 32; m; m >>= 1) cw += __shfl_xor(cw, m);
        float inv = 1.f / fmaxf(cw, 1.f);
        a0.x *= inv; a0.y *= inv; a0.z *= inv; a0.w *= inv;
        a1.x *= inv; a1.y *= inv; a1.z *= inv; a1.w *= inv;
        e4[l] = a0;
        ushort4 u0; u0.x = f2bf_rne(a0.x); u0.y = f2bf_rne(a0.y); u0.z = f2bf_rne(a0.z); u0.w = f2bf_rne(a0.w);
        ((ushort4*)(embh + (size_t)i * CC))[l] = u0;
        if (l < 32) {
            e4[64 + l] = a1;
            ushort4 u1; u1.x = f2bf_rne(a1.x); u1.y = f2bf_rne(a1.y); u1.z = f2bf_rne(a1.z); u1.w = f2bf_rne(a1.w);
            ((ushort4*)(embh + (size_t)i * CC))[64 + l] = u1;
        }
        float ss = a0.x * a0.x + a0.y * a0.y + a0.z * a0.z + a0.w * a0.w
                 + a1.x * a1.x + a1.y * a1.y + a1.z * a1.z + a1.w * a1.w;
#pragma unroll
        for (int m = 32; m; m >>= 1) ss += __shfl_xor(ss, m);
        if (l == 0) xn[i] = ss;
    }
}

// ---------------- K5: 128x128 bf16 MFMA GEMM + fused row-min (u32 keys) ----------------
template <bool REGB>
__global__ __launch_bounds__(256) void k_gemm(
        const unsigned short* __restrict__ Ah, const unsigned short* __restrict__ Bh,
        const float* __restrict__ Bf,
        const float* __restrict__ xn, const float* __restrict__ yn,
        unsigned* __restrict__ partials) {
    __shared__ bf16x8 As[8][128];
    __shared__ bf16x8 Bs[8][128];
    __shared__ unsigned rowbest[128];
    int bid = blockIdx.x;
    int swz = (bid & 7) * 1024 + (bid >> 3);
    int rb = swz & 15, nb = swz >> 4;
    int t = threadIdx.x;
    int w = t >> 6, l = t & 63;
    int wm = w & 1, wn = w >> 1;

    if (t < 128) rowbest[t] = 0xFFFFFFFFu;

    fx16 acc00, acc01, acc10, acc11;
#pragma unroll
    for (int p = 0; p < 16; p++) { acc00[p] = 0.f; acc01[p] = 0.f; acc10[p] = 0.f; acc11[p] = 0.f; }

    const unsigned short* Abase = Ah + (size_t)(rb * 128) * CC;
    const unsigned short* Bbase = REGB ? nullptr : (Bh + (size_t)(nb * 128) * CC);
    const float* Bfbase = Bf + (size_t)(nb * 128) * CC;

    for (int kt = 0; kt < 6; kt++) {
        int k0 = kt * 64;
#pragma unroll
        for (int q = 0; q < 4; q++) {
            int c = q * 256 + t;
            int r = c & 127, g = c >> 7;
            gl_lds16(Abase + (size_t)r * CC + k0 + g * 8, &As[g][r]);
            if (!REGB) {
                gl_lds16(Bbase + (size_t)r * CC + k0 + g * 8, &Bs[g][r]);
            } else {
                const float* src = Bfbase + (size_t)r * CC + k0 + g * 8;
                float4 v0 = *(const float4*)(src);
                float4 v1 = *(const float4*)(src + 4);
                Bs[g][r] = pack8(v0, v1);
            }
        }
        __syncthreads();
#pragma unroll
        for (int s = 0; s < 4; s++) {
            int g = s * 2 + (l >> 5);
            bf16x8 a0 = As[g][wm * 64 + (l & 31)];
            bf16x8 a1 = As[g][wm * 64 + 32 + (l & 31)];
            bf16x8 b0 = Bs[g][wn * 64 + (l & 31)];
            bf16x8 b1 = Bs[g][wn * 64 + 32 + (l & 31)];
            acc00 = __builtin_amdgcn_mfma_f32_32x32x16_bf16(a0, b0, acc00, 0, 0, 0);
            acc01 = __builtin_amdgcn_mfma_f32_32x32x16_bf16(a0, b1, acc01, 0, 0, 0);
            acc10 = __builtin_amdgcn_mfma_f32_32x32x16_bf16(a1, b0, acc10, 0, 0, 0);
            acc11 = __builtin_amdgcn_mfma_f32_32x32x16_bf16(a1, b1, acc11, 0, 0, 0);
        }
        __syncthreads();
    }

    int coll0 = wn * 64 + (l & 31);
    int coll1 = coll0 + 32;
    float yn0 = yn[nb * 128 + coll0], yn1 = yn[nb * 128 + coll1];
#pragma unroll
    for (int i = 0; i < 2; i++) {
#pragma unroll
        for (int p = 0; p < 16; p++) {
            float a0v = (i == 0) ? acc00[p] : acc10[p];
            float a1v = (i == 0) ? acc01[p] : acc11[p];
            int rl = i * 32 + (p & 3) + 8 * (p >> 2) + 4 * (l >> 5);
            float xr = xn[rb * 128 + wm * 64 + rl];
            float d0 = fmaxf(xr - 2.f * a0v + yn0, 0.f);
            float d1 = fmaxf(xr - 2.f * a1v + yn1, 0.f);
            unsigned k0 = (__float_as_uint(d0) & 0xFFFFFF00u) | (unsigned)coll0;
            unsigned k1 = (__float_as_uint(d1) & 0xFFFFFF00u) | (unsigned)coll1;
            unsigned best = k0 < k1 ? k0 : k1;
#pragma unroll
            for (int m = 1; m < 32; m <<= 1) {
                unsigned o2 = __shfl_xor(best, m);
                if (o2 < best) best = o2;
            }
            if ((l & 31) == 0) atomicMin(&rowbest[wm * 64 + rl], best);
        }
    }
    __syncthreads();
    if (t < 128) partials[(size_t)nb * GM + rb * 128 + t] = rowbest[t];
}

// ---------------- K_redcand: full min over 512 nb + scores + per-batch top-4 ----------------
__global__ void k_redcand(const unsigned* __restrict__ partials,
                          float* __restrict__ scores, int* __restrict__ cand) {
    __shared__ unsigned long long key[256];
    __shared__ unsigned long long red[256];
    int b = blockIdx.x, t = threadIdx.x;
    int row = b * 256 + t;
    unsigned long long m = ~0ull;
#pragma unroll 8
    for (int nb = 0; nb < MM / 128; nb++) {
        unsigned k = partials[(size_t)nb * GM + row];
        unsigned long long v = ((unsigned long long)(k & 0xFFFFFF00u) << 32)
                             | (unsigned)(nb * 128 + (k & 0xFFu));
        if (v < m) m = v;
    }
    float sc = sqrtf(__uint_as_float((unsigned)(m >> 32)));
    scores[row] = sc;
    key[t] = ((unsigned long long)__float_as_uint(sc) << 32) | (unsigned)(255 - t);
    __syncthreads();
    for (int k = 0; k < 4; k++) {
        red[t] = key[t];
        __syncthreads();
        for (int s = 128; s; s >>= 1) {
            if (t < s && red[t + s] > red[t]) red[t] = red[t + s];
            __syncthreads();
        }
        unsigned long long win = red[0];
        int patch = 255 - (int)(win & 0xffffffffu);
        if (t == 0) cand[b * 4 + k] = b * SS + patch;
        __syncthreads();
        if (t == patch) key[t] = 0;
        __syncthreads();
    }
}

// ---------------- K_refmap: refine3 (blocks 0..RFB3-1) + map scatter (RFB3..RFB3+MAPB-1) ----
__global__ __launch_bounds__(256) void k_refmap(
        const float* __restrict__ emb, const float* __restrict__ mb,
        const float* __restrict__ xn, const float* __restrict__ yn,
        const int* __restrict__ cand, unsigned long long* __restrict__ refpart,
        const float* __restrict__ scores, const int* __restrict__ labels,
        float* __restrict__ out) {
    int t = threadIdx.x;
    if (blockIdx.x >= RFB3) {
        size_t i4 = (size_t)(blockIdx.x - RFB3) * 256 + t;
        int b = (int)(i4 / (HWP / 4));
        int4 lv = ((const int4*)labels)[i4];
        const float* sb = scores + b * SS;
        float4 o;
        o.x = sb[lv.x]; o.y = sb[lv.y]; o.z = sb[lv.z]; o.w = sb[lv.w];
        ((float4*)out)[i4] = o;
        return;
    }
    __shared__ float clT[CC][32];
    __shared__ float xnc[32];
    __shared__ int cr[32];
    __shared__ unsigned long long wbest[4][64];
    int w = t >> 6, l = t & 63;
    if (t < 32) cr[t] = cand[t];
    __syncthreads();
    if (t < 32) xnc[t] = xn[cr[t]];
    {
        int j = t & 31;
        int r = cr[j];
        for (int kk = t >> 5; kk < CC; kk += 8)
            clT[kk][j] = emb[(size_t)r * CC + kk];
    }
    __syncthreads();

    int j = l & 31;
    int half = l >> 5;
    unsigned long long best = ~0ull;
#pragma unroll
    for (int pr = 0; pr < 8; pr++) {
        int m = blockIdx.x * 64 + w * 16 + pr * 2 + half;
        const float4* r4 = (const float4*)(mb + (size_t)m * CC);
        float s = 0.f;
#pragma unroll 8
        for (int k4 = 0; k4 < CC / 4; k4++) {
            float4 v = r4[k4];
            s = fmaf(v.x, clT[k4 * 4 + 0][j], s);
            s = fmaf(v.y, clT[k4 * 4 + 1][j], s);
            s = fmaf(v.z, clT[k4 * 4 + 2][j], s);
            s = fmaf(v.w, clT[k4 * 4 + 3][j], s);
        }
        float d2 = fmaxf(xnc[j] - 2.f * s + yn[m], 0.f);
        unsigned long long key = ((unsigned long long)__float_as_uint(d2) << 32) | (unsigned)m;
        if (key < best) best = key;
    }
    wbest[w][l] = best;
    __syncthreads();
    if (t < 32) {
        unsigned long long m = ~0ull;
#pragma unroll
        for (int ww = 0; ww < 4; ww++) {
            if (wbest[ww][t] < m) m = wbest[ww][t];
            if (wbest[ww][t + 32] < m) m = wbest[ww][t + 32];
        }
        refpart[(size_t)blockIdx.x * 32 + t] = m;
    }
}

__global__ void k_refred(const unsigned long long* __restrict__ refpart,
                         unsigned long long* __restrict__ keys2) {
    __shared__ unsigned long long red[256];
    int j = blockIdx.x, t = threadIdx.x;
    unsigned long long m = ~0ull;
    for (int i = t; i < RFB3; i += 256) {
        unsigned long long v = refpart[(size_t)i * 32 + j];
        if (v < m) m = v;
    }
    red[t] = m;
    __syncthreads();
    for (int s = 128; s; s >>= 1) {
        if (t < s && red[t + s] < red[t]) red[t] = red[t + s];
        __syncthreads();
    }
    if (t == 0) keys2[j] = red[0];
}

// per-batch selection from keys2/cand (replicated inline; tiny)
__device__ __forceinline__ void final_select(const unsigned long long* keys2, const int* cand,
                                             int b, int& mp_o, float& sc_o, int& nn_o) {
    float bestsc = -1.f;
    int bestpatch = 1 << 20, bestnn = 0;
#pragma unroll
    for (int k = 0; k < 4; k++) {
        unsigned long long key = keys2[b * 4 + k];
        float sc = sqrtf(__uint_as_float((unsigned)(key >> 32)));
        int patch = cand[b * 4 + k] & 255;
        int nnidx = (int)(key & 0xffffffffu);
        if (sc > bestsc || (sc == bestsc && patch < bestpatch)) {
            bestsc = sc; bestpatch = patch; bestnn = nnidx;
        }
    }
    mp_o = bestpatch; sc_o = bestsc; nn_o = bestnn;
}

// ---------------- K12: d_nn — inline final-select, lane-owns-(b,m) serial dots ----------------
__global__ __launch_bounds__(256) void k_dnn3f(const float* __restrict__ mb,
                                               const float* __restrict__ yn,
                                               const unsigned long long* __restrict__ keys2,
                                               const int* __restrict__ cand,
                                               float* __restrict__ dnn) {
    __shared__ float4 nnT[CC / 4][BB];
    __shared__ float ynn[BB];
    __shared__ int nn_l[BB];
    int t = threadIdx.x, w = t >> 6, l = t & 63;
    if (t < BB) {
        int mp_d; float sc_d; int nn_d;
        final_select(keys2, cand, t, mp_d, sc_d, nn_d);
        nn_l[t] = nn_d;
        ynn[t] = yn[nn_d];
    }
    __syncthreads();
    for (int i = t; i < (CC / 4) * BB; i += 256) {
        int k4 = i >> 3, b = i & 7;
        nnT[k4][b] = ((const float4*)(mb + (size_t)nn_l[b] * CC))[k4];
    }
    __syncthreads();

    int b = l & 7, mg = l >> 3;
    int m = blockIdx.x * 32 + w * 8 + mg;
    const float4* r4 = (const float4*)(mb + (size_t)m * CC);
    float s = 0.f;
#pragma unroll 8
    for (int k4 = 0; k4 < CC / 4; k4++) {
        float4 v = r4[k4];
        float4 n = nnT[k4][b];
        s = fmaf(v.x, n.x, s);
        s = fmaf(v.y, n.y, s);
        s = fmaf(v.z, n.z, s);
        s = fmaf(v.w, n.w, s);
    }
    float d2 = fmaxf(ynn[b] - 2.f * s + yn[m], 0.f);
    dnn[(size_t)b * MM + m] = sqrtf(d2);
}

// ---------------- K13a: per-chunk top-9 (64 chunks x 8 batches) ----------------
__global__ void k_top9a(const float* __restrict__ dnn, float* __restrict__ t9v,
                        int* __restrict__ t9i) {
    __shared__ float sd[256][TOPK];
    __shared__ int sx[256][TOPK];
    int c = blockIdx.x, b = blockIdx.y, t = threadIdx.x;
    float ld[TOPK];
    int li[TOPK];
#pragma unroll
    for (int k = 0; k < TOPK; k++) { ld[k] = INFINITY; li[k] = MM; }
    const float* d = dnn + (size_t)b * MM;
    for (int m = c * 1024 + t; m < (c + 1) * 1024; m += 256) {
        float v = d[m];
        if (v < ld[TOPK - 1] || (v == ld[TOPK - 1] && m < li[TOPK - 1])) {
            int k = TOPK - 1;
            while (k > 0 && (v < ld[k - 1] || (v == ld[k - 1] && m < li[k - 1]))) {
                ld[k] = ld[k - 1]; li[k] = li[k - 1]; k--;
            }
            ld[k] = v; li[k] = m;
        }
    }
    for (int k = 0; k < TOPK; k++) { sd[t][k] = ld[k]; sx[t][k] = li[k]; }
    __syncthreads();
    for (int s = 128; s; s >>= 1) {
        if (t < s) {
            float md[TOPK]; int mi[TOPK];
            int p = 0, q = 0;
            for (int k = 0; k < TOPK; k++) {
                float va = sd[t][p], vb = sd[t + s][q];
                int ia = sx[t][p], ib = sx[t + s][q];
                bool ta = (va < vb) || (va == vb && ia < ib);
                if (ta) { md[k] = va; mi[k] = ia; p++; }
                else    { md[k] = vb; mi[k] = ib; q++; }
            }
            for (int k = 0; k < TOPK; k++) { sd[t][k] = md[k]; sx[t][k] = mi[k]; }
        }
        __syncthreads();
    }
    if (t < TOPK) {
        t9v[(b * 64 + c) * TOPK + t] = sd[0][t];
        t9i[(b * 64 + c) * TOPK + t] = sx[0][t];
    }
}

// ---------------- K13b+K14: merge top-9 + pred_score (inline final-select) ----------------
__global__ void k_fintopf(const float* __restrict__ t9v, const int* __restrict__ t9i,
                          const float* __restrict__ emb, const float* __restrict__ mb,
                          const float* __restrict__ yn, const float* __restrict__ xn,
                          const unsigned long long* __restrict__ keys2,
                          const int* __restrict__ cand,
                          float* __restrict__ outp) {
    __shared__ float sd[256][TOPK];
    __shared__ int sx[256][TOPK];
    __shared__ int supl[TOPK];
    __shared__ float ds[TOPK];
    __shared__ int mpb_s;
    __shared__ float scb_s;
    int b = blockIdx.x, t = threadIdx.x;
    if (t == 0) {
        int mp_d; float sc_d; int nn_d;
        final_select(keys2, cand, b, mp_d, sc_d, nn_d);
        mpb_s = mp_d; scb_s = sc_d;
    }
    float ld[TOPK];
    int li[TOPK];
#pragma unroll
    for (int k = 0; k < TOPK; k++) { ld[k] = INFINITY; li[k] = MM; }
    for (int i = t; i < 64 * TOPK; i += 256) {
        float v = t9v[b * 64 * TOPK + i];
        int m = t9i[b * 64 * TOPK + i];
        if (v < ld[TOPK - 1] || (v == ld[TOPK - 1] && m < li[TOPK - 1])) {
            int k = TOPK - 1;
            while (k > 0 && (v < ld[k - 1] || (v == ld[k - 1] && m < li[k - 1]))) {
                ld[k] = ld[k - 1]; li[k] = li[k - 1]; k--;
            }
            ld[k] = v; li[k] = m;
        }
    }
    for (int k = 0; k < TOPK; k++) { sd[t][k] = ld[k]; sx[t][k] = li[k]; }
    __syncthreads();
    for (int s = 128; s; s >>= 1) {
        if (t < s) {
            float md[TOPK]; int mi[TOPK];
            int p = 0, q = 0;
            for (int k = 0; k < TOPK; k++) {
                float va = sd[t][p], vb = sd[t + s][q];
                int ia = sx[t][p], ib = sx[t + s][q];
                bool ta = (va < vb) || (va == vb && ia < ib);
                if (ta) { md[k] = va; mi[k] = ia; p++; }
                else    { md[k] = vb; mi[k] = ib; q++; }
            }
            for (int k = 0; k < TOPK; k++) { sd[t][k] = md[k]; sx[t][k] = mi[k]; }
        }
        __syncthreads();
    }
    if (t < TOPK) supl[t] = sx[0][t];
    __syncthreads();

    int w = t >> 6, l = t & 63;
    int mpb = mpb_s;
    const float* mf = emb + ((size_t)b * SS + mpb) * CC;
    float xr = xn[b * SS + mpb];
    for (int k = w; k < TOPK; k += 4) {
        int sidx = supl[k];
        const float* sr = mb + (size_t)sidx * CC;
        float s = 0.f;
#pragma unroll
        for (int i = 0; i < 6; i++) s = fmaf(mf[i * 64 + l], sr[i * 64 + l], s);
#pragma unroll
        for (int mm = 32; mm; mm >>= 1) s += __shfl_xor(s, mm);
        if (l == 0) ds[k] = sqrtf(fmaxf(xr - 2.f * s + yn[sidx], 0.f));
    }
    __syncthreads();
    if (t == 0) {
        float mx = ds[0];
        for (int k = 1; k < TOPK; k++) mx = fmaxf(mx, ds[k]);
        float num = expf(ds[0] - mx), den = 0.f;
        for (int k = 0; k < TOPK; k++) den += expf(ds[k] - mx);
        outp[b] = (1.f - num / den) * scb_s;
    }
}

extern "C" void kernel_launch(void* const* d_in, const int* in_sizes, int n_in,
                              void* d_out, int out_size, void* d_ws, size_t ws_size,
                              hipStream_t stream) {
    const float* feats  = (const float*)d_in[0];
    const int*   labels = (const int*)d_in[1];
    const float* mb     = (const float*)d_in[2];
    float* out = (float*)d_out;

    char* ws = (char*)d_ws;
    const size_t SZ_MBH   = (size_t)MM * CC * 2;              // 50.3 MB
    const size_t SZ_EMBH  = (size_t)GM * CC * 2;
    const size_t SZ_EMB   = (size_t)GM * CC * 4;
    const size_t SZ_YN    = (size_t)MM * 4;
    const size_t SZ_SMALL = 8192;
    const size_t SZ_CNTS  = (size_t)49 * BB * SS * 4;         // 401 KB
    const size_t SZ_T9    = (size_t)BB * 64 * TOPK * 4;
    const size_t SZ_KCP   = (size_t)NKC * BB * SS * CC * 4;   // 50.3 MB
    const size_t SZ_BIG   = SZ_KCP;

    size_t need_full = SZ_MBH + SZ_EMBH + SZ_EMB + SZ_YN + 2 * SZ_SMALL + SZ_CNTS + 2048
                     + 2 * SZ_T9 + SZ_BIG + 1024;
    bool lowmem = ws_size < need_full;

    size_t o = 0;
    unsigned short* mbh = nullptr;
    if (!lowmem) { mbh = (unsigned short*)(ws + o); o += SZ_MBH; }
    unsigned short* embh = (unsigned short*)(ws + o); o += SZ_EMBH;
    float* emb = (float*)(ws + o);                    o += SZ_EMB;
    float* yn  = (float*)(ws + o);                    o += SZ_YN;
    float* xn  = (float*)(ws + o);                    o += SZ_SMALL;
    float* scores = (float*)(ws + o);                 o += SZ_SMALL;
    unsigned* cntS = (unsigned*)(ws + o);             o += SZ_CNTS;
    int*   cand   = (int*)(ws + o);                   o += 256;
    unsigned long long* keys2 = (unsigned long long*)(ws + o); o += 256;
    o = (o + 255) & ~(size_t)255;
    float* t9v = (float*)(ws + o);                    o += SZ_T9;
    int*   t9i = (int*)(ws + o);                      o += SZ_T9;
    o = (o + 255) & ~(size_t)255;
    char* big = ws + o;
    float* kcpart = (float*)big;                                   // segsum partials
    unsigned* partials = (unsigned*)big;                           // gemm u32 partials (after kcpart dead)
    unsigned long long* refpart  = (unsigned long long*)big;       // after partials consumed (256 KB)
    float* dnn = (float*)(big + 4194304);                          // disjoint from refpart

    if (!lowmem) {
        k_segsum7c<false><<<dim3(NKC, 6, BB), 256, 0, stream>>>(feats, labels, kcpart, cntS);
        k_prep<<<MM / 16 + GM / 4, 256, 0, stream>>>(mb, mbh, yn, kcpart, cntS, emb, xn, embh);
        k_gemm<false><<<8192, 256, 0, stream>>>(embh, mbh, mb, xn, yn, partials);
    } else {
        hipMemsetAsync(emb, 0, SZ_EMB, stream);
        k_segsum7c<true><<<dim3(NKC, 6, BB), 256, 0, stream>>>(feats, labels, emb, cntS);
        k_prep_lm<<<MM / 16 + GM / 4, 256, 0, stream>>>(mb, yn, emb, cntS, xn, embh);
        k_gemm<true><<<8192, 256, 0, stream>>>(embh, embh, mb, xn, yn, partials);
    }

    k_redcand<<<BB, 256, 0, stream>>>(partials, scores, cand);
    k_refmap<<<RFB3 + MAPB, 256, 0, stream>>>(emb, mb, xn, yn, cand, refpart, scores, labels, out);
    k_refred<<<32, 256, 0, stream>>>(refpart, keys2);
    k_dnn3f<<<MM / 32, 256, 0, stream>>>(mb, yn, keys2, cand, dnn);
    k_top9a<<<dim3(64, BB), 256, 0, stream>>>(dnn, t9v, t9i);
    k_fintopf<<<BB, 256, 0, stream>>>(t9v, t9i, emb, mb, yn, xn, keys2, cand, out + (size_t)BB * HWP);
}

// Round 13
// 594.465 us; speedup vs baseline: 1.0649x; 1.0649x over previous
//
#include <hip/hip_runtime.h>

#define BB 8
#define CC 384
#define HWP 50176
#define SS 256
#define MM 65536
#define TOPK 9
#define GM 2048          // BB*SS emb rows
#define NKC 16           // K-split blocks for segsum
#define RFB3 1024        // refine blocks (64 m each)
#define MAPB 392         // map blocks (BB*HWP/4/256)

typedef __attribute__((ext_vector_type(8))) __bf16 bf16x8;
typedef __attribute__((ext_vector_type(16))) float fx16;
typedef __attribute__((ext_vector_type(4))) float f32x4;

__device__ __forceinline__ unsigned short f2bf_rne(float x) {
    unsigned u = __float_as_uint(x);
    unsigned r = (u + 0x7FFFu + ((u >> 16) & 1u)) >> 16;
    return (unsigned short)r;
}

__device__ __forceinline__ bf16x8 pack8(float4 v0, float4 v1) {
    bf16x8 r;
    r[0] = (__bf16)v0.x; r[1] = (__bf16)v0.y; r[2] = (__bf16)v0.z; r[3] = (__bf16)v0.w;
    r[4] = (__bf16)v1.x; r[5] = (__bf16)v1.y; r[6] = (__bf16)v1.z; r[7] = (__bf16)v1.w;
    return r;
}

__device__ __forceinline__ void gl_lds16(const void* g, void* l) {
    auto gp = (const __attribute__((address_space(1))) unsigned int*)g;
    auto lp = (__attribute__((address_space(3))) unsigned int*)l;
    __builtin_amdgcn_global_load_lds(gp, lp, 16, 0, 0);
}

// ---------------- K2: segment sums as MFMA GEMM + fused per-(kc,b) counts ----------------
template <bool ATOMIC>
__global__ __launch_bounds__(256) void k_segsum7c(const float* __restrict__ feats,
                                                  const int* __restrict__ labels,
                                                  float* __restrict__ outp,
                                                  unsigned* __restrict__ cntS) {
    __shared__ bf16x8 Fs[8][64];
    __shared__ int labL[64];
    __shared__ unsigned cnt[SS];
    int kc = blockIdx.x, cg = blockIdx.y, b = blockIdx.z;
    int t = threadIdx.x, l = t & 63, w = t >> 6;
    int c0b = cg * 64;
    int g16 = l >> 4;
    int rowl = l & 15;

    cnt[t] = 0u;

    f32x4 acc[4][4];
#pragma unroll
    for (int i = 0; i < 4; i++)
#pragma unroll
        for (int j = 0; j < 4; j++) acc[i][j] = (f32x4){0.f, 0.f, 0.f, 0.f};

    const float* fb = feats + ((size_t)b * CC + c0b) * HWP;
    const int* lbase = labels + (size_t)b * HWP + kc * 3136;

    int id0 = t * 2;
    int cl = id0 >> 3, g0 = id0 & 7;
    const float* tbase = fb + (size_t)cl * HWP + kc * 3136 + g0 * 8;

    float4 ra0 = *(const float4*)(tbase + 0);
    float4 ra1 = *(const float4*)(tbase + 4);
    float4 rb0 = *(const float4*)(tbase + 8);
    float4 rb1 = *(const float4*)(tbase + 12);
    int4 rl4 = (t < 16) ? ((const int4*)lbase)[t] : (int4){0, 0, 0, 0};

    for (int tt = 0; tt < 49; tt++) {
        __syncthreads();
        if (t < 16) ((int4*)labL)[t] = rl4;
        Fs[g0][cl] = pack8(ra0, ra1);
        Fs[g0 + 1][cl] = pack8(rb0, rb1);
        if (tt + 1 < 49) {
            const float* nb_ = tbase + (size_t)(tt + 1) * 64;
            ra0 = *(const float4*)(nb_ + 0);
            ra1 = *(const float4*)(nb_ + 4);
            rb0 = *(const float4*)(nb_ + 8);
            rb1 = *(const float4*)(nb_ + 12);
            if (t < 16) rl4 = ((const int4*)(lbase + (tt + 1) * 64))[t];
        }
        __syncthreads();

        if (cg == 0 && t < 64) atomicAdd(&cnt[labL[t]], 1u);

        bf16x8 af0[4], af1[4];
#pragma unroll
        for (int rt = 0; rt < 4; rt++) {
            af0[rt] = Fs[g16][rt * 16 + rowl];
            af1[rt] = Fs[4 + g16][rt * 16 + rowl];
        }
        int4 lo0 = ((int4*)labL)[g16 * 2 + 0];
        int4 hi0 = ((int4*)labL)[g16 * 2 + 1];
        int4 lo1 = ((int4*)labL)[8 + g16 * 2 + 0];
        int4 hi1 = ((int4*)labL)[8 + g16 * 2 + 1];

#pragma unroll
        for (int st = 0; st < 4; st++) {
            int tgt = w * 64 + st * 16 + rowl;
            union { unsigned u[4]; bf16x8 v; } B;
            B.u[0] = (lo0.x == tgt ? 0x3F80u : 0u) | (lo0.y == tgt ? 0x3F800000u : 0u);
            B.u[1] = (lo0.z == tgt ? 0x3F80u : 0u) | (lo0.w == tgt ? 0x3F800000u : 0u);
            B.u[2] = (hi0.x == tgt ? 0x3F80u : 0u) | (hi0.y == tgt ? 0x3F800000u : 0u);
            B.u[3] = (hi0.z == tgt ? 0x3F80u : 0u) | (hi0.w == tgt ? 0x3F800000u : 0u);
#pragma unroll
            for (int rt = 0; rt < 4; rt++)
                acc[rt][st] = __builtin_amdgcn_mfma_f32_16x16x32_bf16(af0[rt], B.v, acc[rt][st], 0, 0, 0);
            B.u[0] = (lo1.x == tgt ? 0x3F80u : 0u) | (lo1.y == tgt ? 0x3F800000u : 0u);
            B.u[1] = (lo1.z == tgt ? 0x3F80u : 0u) | (lo1.w == tgt ? 0x3F800000u : 0u);
            B.u[2] = (hi1.x == tgt ? 0x3F80u : 0u) | (hi1.y == tgt ? 0x3F800000u : 0u);
            B.u[3] = (hi1.z == tgt ? 0x3F80u : 0u) | (hi1.w == tgt ? 0x3F800000u : 0u);
#pragma unroll
            for (int rt = 0; rt < 4; rt++)
                acc[rt][st] = __builtin_amdgcn_mfma_f32_16x16x32_bf16(af1[rt], B.v, acc[rt][st], 0, 0, 0);
        }
    }

    if (ATOMIC) {
#pragma unroll
        for (int rt = 0; rt < 4; rt++)
#pragma unroll
            for (int st = 0; st < 4; st++)
#pragma unroll
                for (int r = 0; r < 4; r++) {
                    int s = w * 64 + st * 16 + rowl;
                    int c = c0b + rt * 16 + g16 * 4 + r;
                    atomicAdd(&outp[((size_t)b * SS + s) * CC + c], acc[rt][st][r]);
                }
    } else {
        float* dst = outp + (size_t)(kc * BB + b) * SS * CC;
#pragma unroll
        for (int rt = 0; rt < 4; rt++)
#pragma unroll
            for (int st = 0; st < 4; st++)
#pragma unroll
                for (int r = 0; r < 4; r++) {
                    int s = w * 64 + st * 16 + rowl;
                    int c = c0b + rt * 16 + g16 * 4 + r;
                    dst[(size_t)s * CC + c] = acc[rt][st][r];
                }
    }
    __syncthreads();
    if (cg == 0) cntS[(kc * BB + b) * SS + t] = cnt[t];
}

// ---------------- K_prep: cvtmb (blocks 0..4095) + embfin (blocks 4096..4607) ----------------
__global__ __launch_bounds__(256) void k_prep(const float* __restrict__ mb,
                                              unsigned short* __restrict__ mbh,
                                              float* __restrict__ yn,
                                              const float* __restrict__ kcpart,
                                              const unsigned* __restrict__ cntS,
                                              float* __restrict__ emb, float* __restrict__ xn,
                                              unsigned short* __restrict__ embh) {
    int w = threadIdx.x >> 6, l = threadIdx.x & 63;
    if (blockIdx.x < MM / 16) {
        int r0 = blockIdx.x * 16 + w * 4;
#pragma unroll
        for (int i = 0; i < 4; i++) {
            int row = r0 + i;
            const float4* src = (const float4*)(mb + (size_t)row * CC);
            float4 a = src[l];
            float4 b2 = {0.f, 0.f, 0.f, 0.f};
            if (l < 32) b2 = src[64 + l];
            ushort4 ua; ua.x = f2bf_rne(a.x); ua.y = f2bf_rne(a.y); ua.z = f2bf_rne(a.z); ua.w = f2bf_rne(a.w);
            ((ushort4*)(mbh + (size_t)row * CC))[l] = ua;
            if (l < 32) {
                ushort4 ub; ub.x = f2bf_rne(b2.x); ub.y = f2bf_rne(b2.y); ub.z = f2bf_rne(b2.z); ub.w = f2bf_rne(b2.w);
                ((ushort4*)(mbh + (size_t)row * CC))[64 + l] = ub;
            }
            float s = a.x * a.x + a.y * a.y + a.z * a.z + a.w * a.w
                    + b2.x * b2.x + b2.y * b2.y + b2.z * b2.z + b2.w * b2.w;
#pragma unroll
            for (int m = 32; m; m >>= 1) s += __shfl_xor(s, m);
            if (l == 0) yn[row] = s;
        }
    } else {
        int i = (blockIdx.x - MM / 16) * 4 + w;
        int b = i >> 8, s256 = i & 255;
        float4 a0 = {0.f, 0.f, 0.f, 0.f}, a1 = {0.f, 0.f, 0.f, 0.f};
#pragma unroll 4
        for (int kc = 0; kc < NKC; kc++) {
            const float4* row = (const float4*)(kcpart + ((size_t)(kc * BB + b) * SS + s256) * CC);
            float4 v = row[l];
            a0.x += v.x; a0.y += v.y; a0.z += v.z; a0.w += v.w;
            if (l < 32) {
                float4 v1 = row[64 + l];
                a1.x += v1.x; a1.y += v1.y; a1.z += v1.z; a1.w += v1.w;
            }
        }
        // count = sum over the NKC written slabs only (lanes >= NKC contribute 0)
        float cw = (l < NKC) ? (float)cntS[(l * BB + b) * SS + s256] : 0.f;
#pragma unroll
        for (int m = 32; m; m >>= 1) cw += __shfl_xor(cw, m);
        float inv = 1.f / fmaxf(cw, 1.f);

        a0.x *= inv; a0.y *= inv; a0.z *= inv; a0.w *= inv;
        a1.x *= inv; a1.y *= inv; a1.z *= inv; a1.w *= inv;
        ((float4*)(emb + (size_t)i * CC))[l] = a0;
        ushort4 u0; u0.x = f2bf_rne(a0.x); u0.y = f2bf_rne(a0.y); u0.z = f2bf_rne(a0.z); u0.w = f2bf_rne(a0.w);
        ((ushort4*)(embh + (size_t)i * CC))[l] = u0;
        if (l < 32) {
            ((float4*)(emb + (size_t)i * CC))[64 + l] = a1;
            ushort4 u1; u1.x = f2bf_rne(a1.x); u1.y = f2bf_rne(a1.y); u1.z = f2bf_rne(a1.z); u1.w = f2bf_rne(a1.w);
            ((ushort4*)(embh + (size_t)i * CC))[64 + l] = u1;
        }
        float ss = a0.x * a0.x + a0.y * a0.y + a0.z * a0.z + a0.w * a0.w
                 + a1.x * a1.x + a1.y * a1.y + a1.z * a1.z + a1.w * a1.w;
#pragma unroll
        for (int m = 32; m; m >>= 1) ss += __shfl_xor(ss, m);
        if (l == 0) xn[i] = ss;
    }
}

// ---------------- K_prep lowmem: ynorm + embfin-in-place ----------------
__global__ __launch_bounds__(256) void k_prep_lm(const float* __restrict__ mb,
                                                 float* __restrict__ yn,
                                                 float* __restrict__ emb,
                                                 const unsigned* __restrict__ cntS,
                                                 float* __restrict__ xn,
                                                 unsigned short* __restrict__ embh) {
    int w = threadIdx.x >> 6, l = threadIdx.x & 63;
    if (blockIdx.x < MM / 16) {
        int r0 = blockIdx.x * 16 + w * 4;
#pragma unroll
        for (int i = 0; i < 4; i++) {
            int row = r0 + i;
            const float4* src = (const float4*)(mb + (size_t)row * CC);
            float4 a = src[l];
            float4 b2 = {0.f, 0.f, 0.f, 0.f};
            if (l < 32) b2 = src[64 + l];
            float s = a.x * a.x + a.y * a.y + a.z * a.z + a.w * a.w
                    + b2.x * b2.x + b2.y * b2.y + b2.z * b2.z + b2.w * b2.w;
#pragma unroll
            for (int m = 32; m; m >>= 1) s += __shfl_xor(s, m);
            if (l == 0) yn[row] = s;
        }
    } else {
        int i = (blockIdx.x - MM / 16) * 4 + w;
        int b = i >> 8, s256 = i & 255;
        float4* e4 = (float4*)(emb + (size_t)i * CC);
        float4 a0 = e4[l];
        float4 a1 = {0.f, 0.f, 0.f, 0.f};
        if (l < 32) a1 = e4[64 + l];
        float cw = (l < NKC) ? (float)cntS[(l * BB + b) * SS + s256] : 0.f;
#pragma unroll
        for (int m = 32; m; m >>= 1) cw += __shfl_xor(cw, m);
        float inv = 1.f / fmaxf(cw, 1.f);
        a0.x *= inv; a0.y *= inv; a0.z *= inv; a0.w *= inv;
        a1.x *= inv; a1.y *= inv; a1.z *= inv; a1.w *= inv;
        e4[l] = a0;
        ushort4 u0; u0.x = f2bf_rne(a0.x); u0.y = f2bf_rne(a0.y); u0.z = f2bf_rne(a0.z); u0.w = f2bf_rne(a0.w);
        ((ushort4*)(embh + (size_t)i * CC))[l] = u0;
        if (l < 32) {
            e4[64 + l] = a1;
            ushort4 u1; u1.x = f2bf_rne(a1.x); u1.y = f2bf_rne(a1.y); u1.z = f2bf_rne(a1.z); u1.w = f2bf_rne(a1.w);
            ((ushort4*)(embh + (size_t)i * CC))[64 + l] = u1;
        }
        float ss = a0.x * a0.x + a0.y * a0.y + a0.z * a0.z + a0.w * a0.w
                 + a1.x * a1.x + a1.y * a1.y + a1.z * a1.z + a1.w * a1.w;
#pragma unroll
        for (int m = 32; m; m >>= 1) ss += __shfl_xor(ss, m);
        if (l == 0) xn[i] = ss;
    }
}

// ---------------- K5: 128x128 bf16 MFMA GEMM + fused row-min (u32 keys, 7-bit col) --------
template <bool REGB>
__global__ __launch_bounds__(256) void k_gemm(
        const unsigned short* __restrict__ Ah, const unsigned short* __restrict__ Bh,
        const float* __restrict__ Bf,
        const float* __restrict__ xn, const float* __restrict__ yn,
        unsigned* __restrict__ partials) {
    __shared__ bf16x8 As[8][128];
    __shared__ bf16x8 Bs[8][128];
    __shared__ unsigned rowbest[128];
    int bid = blockIdx.x;
    int swz = (bid & 7) * 1024 + (bid >> 3);
    int rb = swz & 15, nb = swz >> 4;
    int t = threadIdx.x;
    int w = t >> 6, l = t & 63;
    int wm = w & 1, wn = w >> 1;

    if (t < 128) rowbest[t] = 0xFFFFFFFFu;

    fx16 acc00, acc01, acc10, acc11;
#pragma unroll
    for (int p = 0; p < 16; p++) { acc00[p] = 0.f; acc01[p] = 0.f; acc10[p] = 0.f; acc11[p] = 0.f; }

    const unsigned short* Abase = Ah + (size_t)(rb * 128) * CC;
    const unsigned short* Bbase = REGB ? nullptr : (Bh + (size_t)(nb * 128) * CC);
    const float* Bfbase = Bf + (size_t)(nb * 128) * CC;

    for (int kt = 0; kt < 6; kt++) {
        int k0 = kt * 64;
#pragma unroll
        for (int q = 0; q < 4; q++) {
            int c = q * 256 + t;
            int r = c & 127, g = c >> 7;
            gl_lds16(Abase + (size_t)r * CC + k0 + g * 8, &As[g][r]);
            if (!REGB) {
                gl_lds16(Bbase + (size_t)r * CC + k0 + g * 8, &Bs[g][r]);
            } else {
                const float* src = Bfbase + (size_t)r * CC + k0 + g * 8;
                float4 v0 = *(const float4*)(src);
                float4 v1 = *(const float4*)(src + 4);
                Bs[g][r] = pack8(v0, v1);
            }
        }
        __syncthreads();
#pragma unroll
        for (int s = 0; s < 4; s++) {
            int g = s * 2 + (l >> 5);
            bf16x8 a0 = As[g][wm * 64 + (l & 31)];
            bf16x8 a1 = As[g][wm * 64 + 32 + (l & 31)];
            bf16x8 b0 = Bs[g][wn * 64 + (l & 31)];
            bf16x8 b1 = Bs[g][wn * 64 + 32 + (l & 31)];
            acc00 = __builtin_amdgcn_mfma_f32_32x32x16_bf16(a0, b0, acc00, 0, 0, 0);
            acc01 = __builtin_amdgcn_mfma_f32_32x32x16_bf16(a0, b1, acc01, 0, 0, 0);
            acc10 = __builtin_amdgcn_mfma_f32_32x32x16_bf16(a1, b0, acc10, 0, 0, 0);
            acc11 = __builtin_amdgcn_mfma_f32_32x32x16_bf16(a1, b1, acc11, 0, 0, 0);
        }
        __syncthreads();
    }

    int coll0 = wn * 64 + (l & 31);
    int coll1 = coll0 + 32;
    float yn0 = yn[nb * 128 + coll0], yn1 = yn[nb * 128 + coll1];
#pragma unroll
    for (int i = 0; i < 2; i++) {
#pragma unroll
        for (int p = 0; p < 16; p++) {
            float a0v = (i == 0) ? acc00[p] : acc10[p];
            float a1v = (i == 0) ? acc01[p] : acc11[p];
            int rl = i * 32 + (p & 3) + 8 * (p >> 2) + 4 * (l >> 5);
            float xr = xn[rb * 128 + wm * 64 + rl];
            float d0 = fmaxf(xr - 2.f * a0v + yn0, 0.f);
            float d1 = fmaxf(xr - 2.f * a1v + yn1, 0.f);
            unsigned k0 = (__float_as_uint(d0) & 0xFFFFFF80u) | (unsigned)coll0;
            unsigned k1 = (__float_as_uint(d1) & 0xFFFFFF80u) | (unsigned)coll1;
            unsigned best = k0 < k1 ? k0 : k1;
#pragma unroll
            for (int m = 1; m < 32; m <<= 1) {
                unsigned o2 = __shfl_xor(best, m);
                if (o2 < best) best = o2;
            }
            if ((l & 31) == 0) atomicMin(&rowbest[wm * 64 + rl], best);
        }
    }
    __syncthreads();
    if (t < 128) partials[(size_t)nb * GM + rb * 128 + t] = rowbest[t];
}

// ---------------- K6: expand u32 keys -> u64 global, min over 64 nb (64 blocks) ----------
__global__ void k_reduce1(const unsigned* __restrict__ partials,
                          unsigned long long* __restrict__ partial2) {
    int row = blockIdx.x * 256 + threadIdx.x;
    int ng = blockIdx.y;
    unsigned long long m = ~0ull;
    for (int n = 0; n < 64; n++) {
        int nb = ng * 64 + n;
        unsigned k = partials[(size_t)nb * GM + row];
        unsigned long long v = ((unsigned long long)(k & 0xFFFFFF80u) << 32)
                             | (unsigned)(nb * 128 + (k & 0x7Fu));
        if (v < m) m = v;
    }
    partial2[ng * GM + row] = m;
}

// ---------------- K7: final min over 8 groups + scores + per-batch top-4 ----------------
__global__ void k_redcand(const unsigned long long* __restrict__ partial2,
                          float* __restrict__ scores, int* __restrict__ cand) {
    __shared__ unsigned long long key[256];
    __shared__ unsigned long long red[256];
    int b = blockIdx.x, t = threadIdx.x;
    int row = b * 256 + t;
    unsigned long long m = ~0ull;
#pragma unroll
    for (int g = 0; g < 8; g++) {
        unsigned long long v = partial2[g * GM + row];
        if (v < m) m = v;
    }
    float sc = sqrtf(__uint_as_float((unsigned)(m >> 32)));
    scores[row] = sc;
    key[t] = ((unsigned long long)__float_as_uint(sc) << 32) | (unsigned)(255 - t);
    __syncthreads();
    for (int k = 0; k < 4; k++) {
        red[t] = key[t];
        __syncthreads();
        for (int s = 128; s; s >>= 1) {
            if (t < s && red[t + s] > red[t]) red[t] = red[t + s];
            __syncthreads();
        }
        unsigned long long win = red[0];
        int patch = 255 - (int)(win & 0xffffffffu);
        if (t == 0) cand[b * 4 + k] = b * SS + patch;
        __syncthreads();
        if (t == patch) key[t] = 0;
        __syncthreads();
    }
}

// ---------------- K_refmap: refine3 (blocks 0..RFB3-1) + map scatter (rest) ----------------
__global__ __launch_bounds__(256) void k_refmap(
        const float* __restrict__ emb, const float* __restrict__ mb,
        const float* __restrict__ xn, const float* __restrict__ yn,
        const int* __restrict__ cand, unsigned long long* __restrict__ refpart,
        const float* __restrict__ scores, const int* __restrict__ labels,
        float* __restrict__ out) {
    int t = threadIdx.x;
    if (blockIdx.x >= RFB3) {
        size_t i4 = (size_t)(blockIdx.x - RFB3) * 256 + t;
        int b = (int)(i4 / (HWP / 4));
        int4 lv = ((const int4*)labels)[i4];
        const float* sb = scores + b * SS;
        float4 o;
        o.x = sb[lv.x]; o.y = sb[lv.y]; o.z = sb[lv.z]; o.w = sb[lv.w];
        ((float4*)out)[i4] = o;
        return;
    }
    __shared__ float clT[CC][32];
    __shared__ float xnc[32];
    __shared__ int cr[32];
    __shared__ unsigned long long wbest[4][64];
    int w = t >> 6, l = t & 63;
    if (t < 32) cr[t] = cand[t];
    __syncthreads();
    if (t < 32) xnc[t] = xn[cr[t]];
    {
        int j = t & 31;
        int r = cr[j];
        for (int kk = t >> 5; kk < CC; kk += 8)
            clT[kk][j] = emb[(size_t)r * CC + kk];
    }
    __syncthreads();

    int j = l & 31;
    int half = l >> 5;
    unsigned long long best = ~0ull;
#pragma unroll
    for (int pr = 0; pr < 8; pr++) {
        int m = blockIdx.x * 64 + w * 16 + pr * 2 + half;
        const float4* r4 = (const float4*)(mb + (size_t)m * CC);
        float s = 0.f;
#pragma unroll 8
        for (int k4 = 0; k4 < CC / 4; k4++) {
            float4 v = r4[k4];
            s = fmaf(v.x, clT[k4 * 4 + 0][j], s);
            s = fmaf(v.y, clT[k4 * 4 + 1][j], s);
            s = fmaf(v.z, clT[k4 * 4 + 2][j], s);
            s = fmaf(v.w, clT[k4 * 4 + 3][j], s);
        }
        float d2 = fmaxf(xnc[j] - 2.f * s + yn[m], 0.f);
        unsigned long long key = ((unsigned long long)__float_as_uint(d2) << 32) | (unsigned)m;
        if (key < best) best = key;
    }
    wbest[w][l] = best;
    __syncthreads();
    if (t < 32) {
        unsigned long long m = ~0ull;
#pragma unroll
        for (int ww = 0; ww < 4; ww++) {
            if (wbest[ww][t] < m) m = wbest[ww][t];
            if (wbest[ww][t + 32] < m) m = wbest[ww][t + 32];
        }
        refpart[(size_t)blockIdx.x * 32 + t] = m;
    }
}

__global__ void k_refred(const unsigned long long* __restrict__ refpart,
                         unsigned long long* __restrict__ keys2) {
    __shared__ unsigned long long red[256];
    int j = blockIdx.x, t = threadIdx.x;
    unsigned long long m = ~0ull;
    for (int i = t; i < RFB3; i += 256) {
        unsigned long long v = refpart[(size_t)i * 32 + j];
        if (v < m) m = v;
    }
    red[t] = m;
    __syncthreads();
    for (int s = 128; s; s >>= 1) {
        if (t < s && red[t + s] < red[t]) red[t] = red[t + s];
        __syncthreads();
    }
    if (t == 0) keys2[j] = red[0];
}

__device__ __forceinline__ void final_select(const unsigned long long* keys2, const int* cand,
                                             int b, int& mp_o, float& sc_o, int& nn_o) {
    float bestsc = -1.f;
    int bestpatch = 1 << 20, bestnn = 0;
#pragma unroll
    for (int k = 0; k < 4; k++) {
        unsigned long long key = keys2[b * 4 + k];
        float sc = sqrtf(__uint_as_float((unsigned)(key >> 32)));
        int patch = cand[b * 4 + k] & 255;
        int nnidx = (int)(key & 0xffffffffu);
        if (sc > bestsc || (sc == bestsc && patch < bestpatch)) {
            bestsc = sc; bestpatch = patch; bestnn = nnidx;
        }
    }
    mp_o = bestpatch; sc_o = bestsc; nn_o = bestnn;
}

// ---------------- K12: d_nn — inline final-select, lane-owns-(b,m) serial dots ----------------
__global__ __launch_bounds__(256) void k_dnn3f(const float* __restrict__ mb,
                                               const float* __restrict__ yn,
                                               const unsigned long long* __restrict__ keys2,
                                               const int* __restrict__ cand,
                                               float* __restrict__ dnn) {
    __shared__ float4 nnT[CC / 4][BB];
    __shared__ float ynn[BB];
    __shared__ int nn_l[BB];
    int t = threadIdx.x, w = t >> 6, l = t & 63;
    if (t < BB) {
        int mp_d; float sc_d; int nn_d;
        final_select(keys2, cand, t, mp_d, sc_d, nn_d);
        nn_l[t] = nn_d;
        ynn[t] = yn[nn_d];
    }
    __syncthreads();
    for (int i = t; i < (CC / 4) * BB; i += 256) {
        int k4 = i >> 3, b = i & 7;
        nnT[k4][b] = ((const float4*)(mb + (size_t)nn_l[b] * CC))[k4];
    }
    __syncthreads();

    int b = l & 7, mg = l >> 3;
    int m = blockIdx.x * 32 + w * 8 + mg;
    const float4* r4 = (const float4*)(mb + (size_t)m * CC);
    float s = 0.f;
#pragma unroll 8
    for (int k4 = 0; k4 < CC / 4; k4++) {
        float4 v = r4[k4];
        float4 n = nnT[k4][b];
        s = fmaf(v.x, n.x, s);
        s = fmaf(v.y, n.y, s);
        s = fmaf(v.z, n.z, s);
        s = fmaf(v.w, n.w, s);
    }
    float d2 = fmaxf(ynn[b] - 2.f * s + yn[m], 0.f);
    dnn[(size_t)b * MM + m] = sqrtf(d2);
}

// ---------------- K13a: per-chunk top-9 (64 chunks x 8 batches) ----------------
__global__ void k_top9a(const float* __restrict__ dnn, float* __restrict__ t9v,
                        int* __restrict__ t9i) {
    __shared__ float sd[256][TOPK];
    __shared__ int sx[256][TOPK];
    int c = blockIdx.x, b = blockIdx.y, t = threadIdx.x;
    float ld[TOPK];
    int li[TOPK];
#pragma unroll
    for (int k = 0; k < TOPK; k++) { ld[k] = INFINITY; li[k] = MM; }
    const float* d = dnn + (size_t)b * MM;
    for (int m = c * 1024 + t; m < (c + 1) * 1024; m += 256) {
        float v = d[m];
        if (v < ld[TOPK - 1] || (v == ld[TOPK - 1] && m < li[TOPK - 1])) {
            int k = TOPK - 1;
            while (k > 0 && (v < ld[k - 1] || (v == ld[k - 1] && m < li[k - 1]))) {
                ld[k] = ld[k - 1]; li[k] = li[k - 1]; k--;
            }
            ld[k] = v; li[k] = m;
        }
    }
    for (int k = 0; k < TOPK; k++) { sd[t][k] = ld[k]; sx[t][k] = li[k]; }
    __syncthreads();
    for (int s = 128; s; s >>= 1) {
        if (t < s) {
            float md[TOPK]; int mi[TOPK];
            int p = 0, q = 0;
            for (int k = 0; k < TOPK; k++) {
                float va = sd[t][p], vb = sd[t + s][q];
                int ia = sx[t][p], ib = sx[t + s][q];
                bool ta = (va < vb) || (va == vb && ia < ib);
                if (ta) { md[k] = va; mi[k] = ia; p++; }
                else    { md[k] = vb; mi[k] = ib; q++; }
            }
            for (int k = 0; k < TOPK; k++) { sd[t][k] = md[k]; sx[t][k] = mi[k]; }
        }
        __syncthreads();
    }
    if (t < TOPK) {
        t9v[(b * 64 + c) * TOPK + t] = sd[0][t];
        t9i[(b * 64 + c) * TOPK + t] = sx[0][t];
    }
}

// ---------------- K13b+K14: merge top-9 + pred_score (inline final-select) ----------------
__global__ void k_fintopf(const float* __restrict__ t9v, const int* __restrict__ t9i,
                          const float* __restrict__ emb, const float* __restrict__ mb,
                          const float* __restrict__ yn, const float* __restrict__ xn,
                          const unsigned long long* __restrict__ keys2,
                          const int* __restrict__ cand,
                          float* __restrict__ outp) {
    __shared__ float sd[256][TOPK];
    __shared__ int sx[256][TOPK];
    __shared__ int supl[TOPK];
    __shared__ float ds[TOPK];
    __shared__ int mpb_s;
    __shared__ float scb_s;
    int b = blockIdx.x, t = threadIdx.x;
    if (t == 0) {
        int mp_d; float sc_d; int nn_d;
        final_select(keys2, cand, b, mp_d, sc_d, nn_d);
        mpb_s = mp_d; scb_s = sc_d;
    }
    float ld[TOPK];
    int li[TOPK];
#pragma unroll
    for (int k = 0; k < TOPK; k++) { ld[k] = INFINITY; li[k] = MM; }
    for (int i = t; i < 64 * TOPK; i += 256) {
        float v = t9v[b * 64 * TOPK + i];
        int m = t9i[b * 64 * TOPK + i];
        if (v < ld[TOPK - 1] || (v == ld[TOPK - 1] && m < li[TOPK - 1])) {
            int k = TOPK - 1;
            while (k > 0 && (v < ld[k - 1] || (v == ld[k - 1] && m < li[k - 1]))) {
                ld[k] = ld[k - 1]; li[k] = li[k - 1]; k--;
            }
            ld[k] = v; li[k] = m;
        }
    }
    for (int k = 0; k < TOPK; k++) { sd[t][k] = ld[k]; sx[t][k] = li[k]; }
    __syncthreads();
    for (int s = 128; s; s >>= 1) {
        if (t < s) {
            float md[TOPK]; int mi[TOPK];
            int p = 0, q = 0;
            for (int k = 0; k < TOPK; k++) {
                float va = sd[t][p], vb = sd[t + s][q];
                int ia = sx[t][p], ib = sx[t + s][q];
                bool ta = (va < vb) || (va == vb && ia < ib);
                if (ta) { md[k] = va; mi[k] = ia; p++; }
                else    { md[k] = vb; mi[k] = ib; q++; }
            }
            for (int k = 0; k < TOPK; k++) { sd[t][k] = md[k]; sx[t][k] = mi[k]; }
        }
        __syncthreads();
    }
    if (t < TOPK) supl[t] = sx[0][t];
    __syncthreads();

    int w = t >> 6, l = t & 63;
    int mpb = mpb_s;
    const float* mf = emb + ((size_t)b * SS + mpb) * CC;
    float xr = xn[b * SS + mpb];
    for (int k = w; k < TOPK; k += 4) {
        int sidx = supl[k];
        const float* sr = mb + (size_t)sidx * CC;
        float s = 0.f;
#pragma unroll
        for (int i = 0; i < 6; i++) s = fmaf(mf[i * 64 + l], sr[i * 64 + l], s);
#pragma unroll
        for (int mm = 32; mm; mm >>= 1) s += __shfl_xor(s, mm);
        if (l == 0) ds[k] = sqrtf(fmaxf(xr - 2.f * s + yn[sidx], 0.f));
    }
    __syncthreads();
    if (t == 0) {
        float mx = ds[0];
        for (int k = 1; k < TOPK; k++) mx = fmaxf(mx, ds[k]);
        float num = expf(ds[0] - mx), den = 0.f;
        for (int k = 0; k < TOPK; k++) den += expf(ds[k] - mx);
        outp[b] = (1.f - num / den) * scb_s;
    }
}

extern "C" void kernel_launch(void* const* d_in, const int* in_sizes, int n_in,
                              void* d_out, int out_size, void* d_ws, size_t ws_size,
                              hipStream_t stream) {
    const float* feats  = (const float*)d_in[0];
    const int*   labels = (const int*)d_in[1];
    const float* mb     = (const float*)d_in[2];
    float* out = (float*)d_out;

    char* ws = (char*)d_ws;
    const size_t SZ_MBH   = (size_t)MM * CC * 2;              // 50.3 MB
    const size_t SZ_EMBH  = (size_t)GM * CC * 2;
    const size_t SZ_EMB   = (size_t)GM * CC * 4;
    const size_t SZ_YN    = (size_t)MM * 4;
    const size_t SZ_SMALL = 8192;
    const size_t SZ_CNTS  = (size_t)NKC * BB * SS * 4;        // 131 KB
    const size_t SZ_P2    = (size_t)8 * GM * 8;
    const size_t SZ_T9    = (size_t)BB * 64 * TOPK * 4;
    const size_t SZ_KCP   = (size_t)NKC * BB * SS * CC * 4;   // 50.3 MB
    const size_t SZ_BIG   = SZ_KCP;

    size_t need_full = SZ_MBH + SZ_EMBH + SZ_EMB + SZ_YN + 2 * SZ_SMALL + SZ_CNTS + 2048
                     + SZ_P2 + 2 * SZ_T9 + SZ_BIG + 1024;
    bool lowmem = ws_size < need_full;

    size_t o = 0;
    unsigned short* mbh = nullptr;
    if (!lowmem) { mbh = (unsigned short*)(ws + o); o += SZ_MBH; }
    unsigned short* embh = (unsigned short*)(ws + o); o += SZ_EMBH;
    float* emb = (float*)(ws + o);                    o += SZ_EMB;
    float* yn  = (float*)(ws + o);                    o += SZ_YN;
    float* xn  = (float*)(ws + o);                    o += SZ_SMALL;
    float* scores = (float*)(ws + o);                 o += SZ_SMALL;
    unsigned* cntS = (unsigned*)(ws + o);             o += SZ_CNTS;
    int*   cand   = (int*)(ws + o);                   o += 256;
    unsigned long long* keys2 = (unsigned long long*)(ws + o); o += 256;
    o = (o + 255) & ~(size_t)255;
    unsigned long long* partial2 = (unsigned long long*)(ws + o); o += SZ_P2;
    float* t9v = (float*)(ws + o);                    o += SZ_T9;
    int*   t9i = (int*)(ws + o);                      o += SZ_T9;
    o = (o + 255) & ~(size_t)255;
    char* big = ws + o;
    float* kcpart = (float*)big;                                   // segsum partials
    unsigned* partials = (unsigned*)big;                           // gemm u32 partials (after kcpart dead)
    unsigned long long* refpart  = (unsigned long long*)big;       // after partials consumed (256 KB)
    float* dnn = (float*)(big + 4194304);                          // disjoint from refpart

    if (!lowmem) {
        k_segsum7c<false><<<dim3(NKC, 6, BB), 256, 0, stream>>>(feats, labels, kcpart, cntS);
        k_prep<<<MM / 16 + GM / 4, 256, 0, stream>>>(mb, mbh, yn, kcpart, cntS, emb, xn, embh);
        k_gemm<false><<<8192, 256, 0, stream>>>(embh, mbh, mb, xn, yn, partials);
    } else {
        hipMemsetAsync(emb, 0, SZ_EMB, stream);
        k_segsum7c<true><<<dim3(NKC, 6, BB), 256, 0, stream>>>(feats, labels, emb, cntS);
        k_prep_lm<<<MM / 16 + GM / 4, 256, 0, stream>>>(mb, yn, emb, cntS, xn, embh);
        k_gemm<true><<<8192, 256, 0, stream>>>(embh, embh, mb, xn, yn, partials);
    }

    k_reduce1<<<dim3(8, 8), 256, 0, stream>>>(partials, partial2);
    k_redcand<<<BB, 256, 0, stream>>>(partial2, scores, cand);
    k_refmap<<<RFB3 + MAPB, 256, 0, stream>>>(emb, mb, xn, yn, cand, refpart, scores, labels, out);
    k_refred<<<32, 256, 0, stream>>>(refpart, keys2);
    k_dnn3f<<<MM / 32, 256, 0, stream>>>(mb, yn, keys2, cand, dnn);
    k_top9a<<<dim3(64, BB), 256, 0, stream>>>(dnn, t9v, t9i);
    k_fintopf<<<BB, 256, 0, stream>>>(t9v, t9i, emb, mb, yn, xn, keys2, cand, out + (size_t)BB * HWP);
}